// Round 12
// baseline (3523.012 us; speedup 1.0000x reference)
//
#include <hip/hip_runtime.h>
#include <hip/hip_bf16.h>
#include <stdint.h>

typedef __bf16 bf16x8 __attribute__((ext_vector_type(8)));
typedef float  f32x16 __attribute__((ext_vector_type(16)));

// ---------- helpers ----------

__device__ __forceinline__ uint32_t rn2_bf16(uint32_t lo, uint32_t hi) {
  uint32_t rlo = (lo + 0x7FFFu + ((lo >> 16) & 1u)) >> 16;
  uint32_t rhi = (hi + 0x7FFFu + ((hi >> 16) & 1u)) >> 16;
  return (rhi << 16) | (rlo & 0xFFFFu);
}

__device__ __forceinline__ uint32_t sign2_bf16(uint32_t lo, uint32_t hi) {
  uint32_t slo = (lo & 0x7FFFFFFFu) ? (0x3F80u | ((lo >> 16) & 0x8000u)) : 0u;
  uint32_t shi = (hi & 0x7FFFFFFFu) ? (0x3F80u | ((hi >> 16) & 0x8000u)) : 0u;
  return (shi << 16) | slo;
}

__device__ __forceinline__ void gl16(const void* g, void* l) {
  __builtin_amdgcn_global_load_lds(
      (const __attribute__((address_space(1))) uint32_t*)g,
      (__attribute__((address_space(3))) uint32_t*)l,
      16, 0, 0);
}

// ---------- prep: f32 row-major -> bf16 K32-plane FRAGMENT-TILE layout ----------
// 16B chunk index = ((kt32*(R/32)+mb)*2 + ks2)*64 + sub*32 + r
// holds rows[mb*32+r], k = kt32*32 + ks2*16 + sub*8 .. +8.
// Each K32 tile of a 256-row band = contiguous 16KB (8 mb x 2 ks x 1KB).

__global__ void prep_frag(const float* __restrict__ x, uint4* __restrict__ xf, int Mx,
                          const float* __restrict__ w, uint4* __restrict__ wf, int Nw,
                          int K) {
  const int kpw = K >> 6;
  const long nxc = ((long)Mx * K) >> 3;
  const long nwc = ((long)Nw * K) >> 3;
  const long stride = (long)gridDim.x * blockDim.x;
  for (long c = (long)blockIdx.x * blockDim.x + threadIdx.x; c < nxc + nwc; c += stride) {
    const bool isX = (c < nxc);
    const float* src = isX ? x : w;
    uint4* dst = isX ? xf : wf;
    const int rows32 = (isX ? Mx : Nw) >> 5;
    const long cc = isX ? c : (c - nxc);

    const int t = (int)(cc & 63);
    const long wv = cc >> 6;
    const int band = (int)(wv / kpw);
    const int kg = (int)(wv % kpw);
    const int row = band * 8 + (t & 7);
    const int k8 = kg * 8 + (t >> 3);

    const int kt32 = k8 >> 2, ks2 = (k8 >> 1) & 1, sub = k8 & 1;
    const int mb = row >> 5, r = row & 31;
    const long out16 = ((long)(kt32 * rows32 + mb) * 2 + ks2) * 64 + sub * 32 + r;

    const uint4* s = reinterpret_cast<const uint4*>(src + (long)row * K + k8 * 8);
    uint4 a = s[0], b = s[1];
    uint4 o;
    if (isX) {
      o.x = rn2_bf16(a.x, a.y); o.y = rn2_bf16(a.z, a.w);
      o.z = rn2_bf16(b.x, b.y); o.w = rn2_bf16(b.z, b.w);
    } else {
      o.x = sign2_bf16(a.x, a.y); o.y = sign2_bf16(a.z, a.w);
      o.z = sign2_bf16(b.x, b.y); o.w = sign2_bf16(b.z, b.w);
    }
    dst[out16] = o;
  }
}

// ---------- 256x256 GEMM, 32x32x16 MFMA, BK=32, 64KB LDS -> 2 blocks/CU ----------
// R10/R11 failed with a DETERMINISTIC cross-wave race: VM0 at phase START
// (after BARX) only proves the OWN wave's DMA landed; reads in the same phase
// then sample other waves' slices before THEIR DMA lands. The R6-R9 invariant
// is VM0 -> BARX -> reads. Restored here:
//   VM0 at END of ph1 (drains tile(2t+2), issued ph0, ~2-phase flight) ->
//     BARX -> ph2 reads buf0.
//   VM0 at END of ph3 (drains tile(2t+3), issued ph2) -> BARX -> ph0' reads
//     buf1.
//   Prologue: VMN4+BARX (tile0 visible) -> priming reads -> VM0+BARX (tile1
//     visible + 1-barrier gap before ph0's buf0 overwrite).
// Stage-after-read: ph3 reads buf0 -> BARX -> ph0 STG buf0; ph1 reads buf1 ->
// BARX -> ph2 STG buf1 (1-barrier discipline, R6-R9 precedent).

#define BARX()  do { __builtin_amdgcn_s_barrier(); \
                     __builtin_amdgcn_sched_barrier(0); } while (0)
#define VM0()   asm volatile("s_waitcnt vmcnt(0)" ::: "memory")
#define VMN4()  asm volatile("s_waitcnt vmcnt(4)" ::: "memory")
#define SGB(m, n) __builtin_amdgcn_sched_group_barrier((m), (n), 0)
#define MF(a, b, c) __builtin_amdgcn_mfma_f32_32x32x16_bf16((a), (b), (c), 0, 0, 0)

// (DS_READ,MFMA)x6 then MFMAx2
#define PIN6() do { \
    SGB(0x100,1); SGB(0x8,1); SGB(0x100,1); SGB(0x8,1); \
    SGB(0x100,1); SGB(0x8,1); SGB(0x100,1); SGB(0x8,1); \
    SGB(0x100,1); SGB(0x8,1); SGB(0x100,1); SGB(0x8,1); \
    SGB(0x8,2); } while (0)
// 4 global_load_lds first (staging phases)
#define PINV() SGB(0x20,4)

__global__ __launch_bounds__(512, 4) void gemm256(
    const uint16_t* __restrict__ Af,  // K32-plane fragment-tile bf16
    const uint16_t* __restrict__ Bf,  // K32-plane fragment-tile sign bf16
    const float* __restrict__ bias,   // [N]
    float* __restrict__ C,            // [M][N] f32
    int M, int N, int K) {
  __shared__ alignas(16) uint8_t L[65536];
  uint8_t* Lb = L;

  const int tid  = threadIdx.x;
  const int lane = tid & 63;
  const int w    = tid >> 6;
  const int wr   = w >> 2;        // 0..1 -> M rows [wr*128, +128)
  const int wc   = w & 3;         // 0..3 -> N cols [wc*64, +64)
  const int l31  = lane & 31;
  const int lhi  = lane >> 5;

  // bijective XCD swizzle (nwg % 8 == 0 guaranteed by launcher)
  const int nbx = N >> 8;
  const int nwg = nbx * (M >> 8);
  const int bid = blockIdx.x;
  const int swb = (bid & 7) * (nwg >> 3) + (bid >> 3);
  const size_t m0 = (size_t)(swb / nbx) << 8;
  const size_t n0 = (size_t)(swb % nbx) << 8;

  const int NT = K >> 5;                        // K32 tiles
  const size_t ktA = (size_t)(M >> 5) * 2048;   // bytes per K32 plane (A)
  const size_t ktB = (size_t)(N >> 5) * 2048;   // bytes per K32 plane (B)
  const char* Abase = (const char*)Af + (m0 >> 5) * 2048;
  const char* Bbase = (const char*)Bf + (n0 >> 5) * 2048;

  const int wB = w << 11;            // wave's 2KB slice of a 16KB region
  const int g0 = wB + lane * 16;
  const int g1 = g0 + 1024;

  // LDS map: buf d at d*32768; A region 16KB at +0, B region 16KB at +16384.
#define STG(LOFF, SRC) do { \
    gl16((SRC) + g0, Lb + (LOFF) + wB); \
    gl16((SRC) + g1, Lb + (LOFF) + wB + 1024); } while (0)

  // frag(mb,q) at (mb*2+q)*1024; A: mb = wr*4+i; B: nb = wc*2+j
#define FRA32(d, i, q) (*reinterpret_cast<const bf16x8*>( \
    Lb + (d) * 32768 + wr * 8192 + (i) * 2048 + (q) * 1024 + lane * 16))
#define FRB32(d, j, q) (*reinterpret_cast<const bf16x8*>( \
    Lb + (d) * 32768 + 16384 + wc * 4096 + (j) * 2048 + (q) * 1024 + lane * 16))

  f32x16 acc[4][2] = {};

  // Interleaved phase: MFMA consumes (CAa,CAb); ds_reads refill (Ra,Rb) for
  // phase s+2. 1:1 weave so both pipes fill from every wave concurrently.
#define QMRD(CAa, CAb, Ra, Rb, d, q) do { \
    Ra[0] = FRA32(d, 0, q); \
    acc[0][0] = MF(CAa[0], CAb[0], acc[0][0]); \
    Ra[1] = FRA32(d, 1, q); \
    acc[0][1] = MF(CAa[0], CAb[1], acc[0][1]); \
    Ra[2] = FRA32(d, 2, q); \
    acc[1][0] = MF(CAa[1], CAb[0], acc[1][0]); \
    Ra[3] = FRA32(d, 3, q); \
    acc[1][1] = MF(CAa[1], CAb[1], acc[1][1]); \
    Rb[0] = FRB32(d, 0, q); \
    acc[2][0] = MF(CAa[2], CAb[0], acc[2][0]); \
    Rb[1] = FRB32(d, 1, q); \
    acc[2][1] = MF(CAa[2], CAb[1], acc[2][1]); \
    acc[3][0] = MF(CAa[3], CAb[0], acc[3][0]); \
    acc[3][1] = MF(CAa[3], CAb[1], acc[3][1]); \
  } while (0)

  // ---- prologue: tile0 -> buf0, tile1 -> buf1; prime S0,S1 from tile0 ----
  STG(0,     Abase);          // t0 A
  STG(16384, Bbase);          // t0 B
  STG(32768, Abase + ktA);    // t1 A
  STG(49152, Bbase + ktB);    // t1 B
  VMN4();   // own t0 loads done
  BARX();   // all waves' t0 writes visible
  bf16x8 S0a[4], S0b[2], S1a[4], S1b[2], S2a[4], S2b[2], S3a[4], S3b[2];
#pragma unroll
  for (int i = 0; i < 4; ++i) S0a[i] = FRA32(0, i, 0);
#pragma unroll
  for (int j = 0; j < 2; ++j) S0b[j] = FRB32(0, j, 0);
#pragma unroll
  for (int i = 0; i < 4; ++i) S1a[i] = FRA32(0, i, 1);
#pragma unroll
  for (int j = 0; j < 2; ++j) S1b[j] = FRB32(0, j, 1);
  VM0();    // own t1 loads done
  BARX();   // all waves' t1 writes visible; 1-barrier gap before buf0 overwrite

  const int T2 = NT >> 1;  // iterations of 2 K32-tiles (4 phases each)
  for (int t = 0; t < T2; ++t) {
    const int u2 = 2 * t + 2, u3 = 2 * t + 3;
    const char* A2 = Abase + (size_t)(u2 < NT ? u2 : NT - 1) * ktA;
    const char* B2 = Bbase + (size_t)(u2 < NT ? u2 : NT - 1) * ktB;
    const char* A3 = Abase + (size_t)(u3 < NT ? u3 : NT - 1) * ktA;
    const char* B3 = Bbase + (size_t)(u3 < NT ? u3 : NT - 1) * ktB;

    // ph0: MFMA tile2t ks0; read buf1 tile(2t+1) ks0 -> S2;
    //      stage tile(2t+2) A+B -> buf0
    STG(0, A2);
    STG(16384, B2);
    QMRD(S0a, S0b, S2a, S2b, 1, 0);
    PINV(); PIN6();
    BARX();

    // ph1: MFMA ks1; read buf1 ks1 -> S3; VM0 (tile 2t+2 landed) -> BARX
    QMRD(S1a, S1b, S3a, S3b, 1, 1);
    PIN6();
    VM0();
    BARX();

    // ph2: MFMA tile(2t+1) ks0; read buf0 tile(2t+2) ks0 -> S0;
    //      stage tile(2t+3) A+B -> buf1
    STG(32768, A3);
    STG(49152, B3);
    QMRD(S2a, S2b, S0a, S0b, 0, 0);
    PINV(); PIN6();
    BARX();

    // ph3: MFMA ks1; read buf0 ks1 -> S1; VM0 (tile 2t+3 landed) -> BARX
    QMRD(S3a, S3b, S1a, S1b, 0, 1);
    PIN6();
    VM0();
    BARX();
  }
  VM0();  // drain in-flight DMA before teardown

  // ---- epilogue: +bias, f32 store ----
  // C/D 32x32: col = lane&31, row = (reg&3) + 8*(reg>>2) + 4*(lane>>5)
#pragma unroll
  for (int i = 0; i < 4; ++i) {
#pragma unroll
    for (int j2 = 0; j2 < 2; ++j2) {
      const size_t col = n0 + wc * 64 + j2 * 32 + l31;
      const float bv = bias[col];
      const size_t rbase = m0 + wr * 128 + i * 32 + lhi * 4;
#pragma unroll
      for (int r = 0; r < 16; ++r) {
        const size_t row = rbase + (r & 3) + 8 * (r >> 2);
        C[row * N + col] = acc[i][j2][r] + bv;
      }
    }
  }
}

// ---------- naive f32 fallback (shape mismatch only) ----------
__global__ void gemm_naive(const float* __restrict__ x, const float* __restrict__ w,
                           const float* __restrict__ b, float* __restrict__ out,
                           int M, int N, int K) {
  int n = blockIdx.x * blockDim.x + threadIdx.x;
  int m = blockIdx.y;
  if (n >= N || m >= M) return;
  float acc = 0.f;
  for (int k = 0; k < K; ++k) {
    float wv = w[(size_t)n * K + k];
    float s = (wv > 0.f) ? 1.f : ((wv < 0.f) ? -1.f : 0.f);
    acc += x[(size_t)m * K + k] * s;
  }
  out[(size_t)m * N + n] = acc + b[n];
}

extern "C" void kernel_launch(void* const* d_in, const int* in_sizes, int n_in,
                              void* d_out, int out_size, void* d_ws, size_t ws_size,
                              hipStream_t stream) {
  const float* x = (const float*)d_in[0];
  const float* w = (const float*)d_in[1];
  const float* b = (const float*)d_in[2];
  float* out = (float*)d_out;

  const int N = in_sizes[2];
  const int K = in_sizes[1] / N;
  const int M = in_sizes[0] / K;

  const size_t need = ((size_t)M * K + (size_t)N * K) * sizeof(uint16_t);
  const bool big_ok = (M % 256 == 0) && (N % 256 == 0) && (K % 256 == 0) &&
                      (((M / 256) * (N / 256)) % 8 == 0) && (ws_size >= need);
  if (!big_ok) {
    hipLaunchKernelGGL(gemm_naive, dim3((N + 255) / 256, M), dim3(256), 0, stream,
                       x, w, b, out, M, N, K);
    return;
  }

  uint16_t* Xf = (uint16_t*)d_ws;
  uint16_t* Wf = Xf + (size_t)M * K;

  hipLaunchKernelGGL(prep_frag, dim3(2048), dim3(256), 0, stream,
                     x, (uint4*)Xf, M, w, (uint4*)Wf, N, K);

  hipLaunchKernelGGL(gemm256, dim3((M / 256) * (N / 256)), dim3(512), 0, stream,
                     Xf, Wf, b, out, M, N, K);
}

// Round 13
// 141.895 us; speedup vs baseline: 24.8283x; 24.8283x over previous
//
#include <hip/hip_runtime.h>
#include <hip/hip_bf16.h>
#include <stdint.h>

typedef __bf16 bf16x8 __attribute__((ext_vector_type(8)));
typedef float  f32x16 __attribute__((ext_vector_type(16)));

// ---------- helpers ----------

__device__ __forceinline__ uint32_t rn2_bf16(uint32_t lo, uint32_t hi) {
  uint32_t rlo = (lo + 0x7FFFu + ((lo >> 16) & 1u)) >> 16;
  uint32_t rhi = (hi + 0x7FFFu + ((hi >> 16) & 1u)) >> 16;
  return (rhi << 16) | (rlo & 0xFFFFu);
}

__device__ __forceinline__ uint32_t sign2_bf16(uint32_t lo, uint32_t hi) {
  uint32_t slo = (lo & 0x7FFFFFFFu) ? (0x3F80u | ((lo >> 16) & 0x8000u)) : 0u;
  uint32_t shi = (hi & 0x7FFFFFFFu) ? (0x3F80u | ((hi >> 16) & 0x8000u)) : 0u;
  return (shi << 16) | slo;
}

__device__ __forceinline__ void gl16(const void* g, void* l) {
  __builtin_amdgcn_global_load_lds(
      (const __attribute__((address_space(1))) uint32_t*)g,
      (__attribute__((address_space(3))) uint32_t*)l,
      16, 0, 0);
}

// ---------- prep: f32 row-major -> bf16 K64-plane FRAGMENT-TILE layout ----------
// (R6/R7/R8-verified)  16B chunk index = ((kt*(R/32)+mb)*4 + ks)*64 + sub*32 + r
// holds rows[mb*32+r], k = kt*64 + ks*16 + sub*8 .. +8.
// Each K64 tile of a 256-row band = contiguous 32KB (8 mb-planes x 4KB).

__global__ void prep_frag(const float* __restrict__ x, uint4* __restrict__ xf, int Mx,
                          const float* __restrict__ w, uint4* __restrict__ wf, int Nw,
                          int K) {
  const int kpw = K >> 6;
  const long nxc = ((long)Mx * K) >> 3;
  const long nwc = ((long)Nw * K) >> 3;
  const long stride = (long)gridDim.x * blockDim.x;
  for (long c = (long)blockIdx.x * blockDim.x + threadIdx.x; c < nxc + nwc; c += stride) {
    const bool isX = (c < nxc);
    const float* src = isX ? x : w;
    uint4* dst = isX ? xf : wf;
    const int rows32 = (isX ? Mx : Nw) >> 5;
    const long cc = isX ? c : (c - nxc);

    const int t = (int)(cc & 63);
    const long wv = cc >> 6;
    const int band = (int)(wv / kpw);
    const int kg = (int)(wv % kpw);
    const int row = band * 8 + (t & 7);
    const int k8 = kg * 8 + (t >> 3);

    const int kt = k8 >> 3, ks = (k8 >> 1) & 3, sub = k8 & 1;
    const int mb = row >> 5, r = row & 31;
    const long out16 = ((long)(kt * rows32 + mb) * 4 + ks) * 64 + sub * 32 + r;

    const uint4* s = reinterpret_cast<const uint4*>(src + (long)row * K + k8 * 8);
    uint4 a = s[0], b = s[1];
    uint4 o;
    if (isX) {
      o.x = rn2_bf16(a.x, a.y); o.y = rn2_bf16(a.z, a.w);
      o.z = rn2_bf16(b.x, b.y); o.w = rn2_bf16(b.z, b.w);
    } else {
      o.x = sign2_bf16(a.x, a.y); o.y = sign2_bf16(a.z, a.w);
      o.z = sign2_bf16(b.x, b.y); o.w = sign2_bf16(b.z, b.w);
    }
    dst[out16] = o;
  }
}

// ---------- 256x256 GEMM, 32x32x16 MFMA, MERGED 4-phase pipeline ----------
// R8 geometry (BK=64, 128KB LDS, 1 block/CU, launch_bounds(512,2) — R12 proved
// (512,4) spills the 128-reg accumulator) with phase PAIRS merged: 4 phases per
// 2 K64-tiles instead of 8 -> half the barriers/VM0 boundaries (R8's ~500cyc/
// phase sync overhead was the dominant non-pipe cost). Each phase: 16 MFMA
// (2 ks-steps, consuming slot filled last phase) || 12 ds_read (next 2 ks) ||
// [8 gl16 staging].  2-deep P/Q slot rotation (96 VGPR frags, same as R8).
// Race discipline (R10/R11 lesson: VM0 -> BARX -> read, per-wave drain first):
//   VM0 end mph0 drains tile(2t+1) (staged mph3-prev, >=1.3 phases) -> BARX ->
//     mph1 reads buf1.
//   VM0 end mph2 drains tile(2t+2) (staged mph1) -> BARX -> mph3 reads buf0.
// Stage-after-read (1-barrier gap): buf0 last read mph0 -> STG mph1;
//   buf1 last read mph2 -> STG mph3.  Prologue primes P after VMN8+BARX; first
//   overwrite of buf0 is mph1 (priming reads 1 barrier earlier via mph0's BARX).

#define BARX()  do { __builtin_amdgcn_s_barrier(); \
                     __builtin_amdgcn_sched_barrier(0); } while (0)
#define VM0()   asm volatile("s_waitcnt vmcnt(0)" ::: "memory")
#define VMN8()  asm volatile("s_waitcnt vmcnt(8)" ::: "memory")
#define SGB(m, n) __builtin_amdgcn_sched_group_barrier((m), (n), 0)
#define MF(a, b, c) __builtin_amdgcn_mfma_f32_32x32x16_bf16((a), (b), (c), 0, 0, 0)

// (DS_READ,MFMA)x12 then MFMAx4
#define PIN12() do { \
    SGB(0x100,1); SGB(0x8,1); SGB(0x100,1); SGB(0x8,1); \
    SGB(0x100,1); SGB(0x8,1); SGB(0x100,1); SGB(0x8,1); \
    SGB(0x100,1); SGB(0x8,1); SGB(0x100,1); SGB(0x8,1); \
    SGB(0x100,1); SGB(0x8,1); SGB(0x100,1); SGB(0x8,1); \
    SGB(0x100,1); SGB(0x8,1); SGB(0x100,1); SGB(0x8,1); \
    SGB(0x100,1); SGB(0x8,1); SGB(0x100,1); SGB(0x8,1); \
    SGB(0x8,4); } while (0)
// 8 global_load_lds first (staging phases)
#define PINV8() SGB(0x20,8)

__global__ __launch_bounds__(512, 2) void gemm256(
    const uint16_t* __restrict__ Af,  // K64-plane fragment-tile bf16
    const uint16_t* __restrict__ Bf,  // K64-plane fragment-tile sign bf16
    const float* __restrict__ bias,   // [N]
    float* __restrict__ C,            // [M][N] f32
    int M, int N, int K) {
  __shared__ alignas(16) uint8_t L[131072];
  uint8_t* Lb = L;

  const int tid  = threadIdx.x;
  const int lane = tid & 63;
  const int w    = tid >> 6;
  const int wr   = w >> 2;        // 0..1 -> M rows [wr*128, +128)
  const int wc   = w & 3;         // 0..3 -> N cols [wc*64, +64)
  const int l31  = lane & 31;
  const int lhi  = lane >> 5;

  // bijective XCD swizzle (nwg % 8 == 0 guaranteed by launcher)
  const int nbx = N >> 8;
  const int nwg = nbx * (M >> 8);
  const int bid = blockIdx.x;
  const int swb = (bid & 7) * (nwg >> 3) + (bid >> 3);
  const size_t m0 = (size_t)(swb / nbx) << 8;
  const size_t n0 = (size_t)(swb % nbx) << 8;

  const int NT = K >> 6;                       // K64 tiles
  const size_t ktA = (size_t)(M >> 5) * 4096;  // bytes per kt plane (A)
  const size_t ktB = (size_t)(N >> 5) * 4096;  // bytes per kt plane (B)
  const char* Abase = (const char*)Af + (m0 >> 5) * 4096;
  const char* Bbase = (const char*)Bf + (n0 >> 5) * 4096;

  const int wB = w << 11;            // wave's 2KB slice of a 16KB half
  const int g0 = wB + lane * 16;
  const int g1 = g0 + 1024;

  // LDS map: buf d at d*65536; A 32KB at +0, B 32KB at +32768.
#define STG(LOFF, SRC) do { \
    gl16((SRC) + g0, Lb + (LOFF) + wB); \
    gl16((SRC) + g1, Lb + (LOFF) + wB + 1024); } while (0)

  // frag(mb,q) at (mb*4+q)*1024; A: mb = wr*4+i; B: nb = wc*2+j
#define FRA32(d, i, q) (*reinterpret_cast<const bf16x8*>( \
    Lb + (d) * 65536 + wr * 16384 + (i) * 4096 + (q) * 1024 + lane * 16))
#define FRB32(d, j, q) (*reinterpret_cast<const bf16x8*>( \
    Lb + (d) * 65536 + 32768 + wc * 8192 + (j) * 4096 + (q) * 1024 + lane * 16))

  f32x16 acc[4][2] = {};

  // Merged phase: 16 MFMA consume slot C (2 ks-steps); 12 ds_reads refill
  // slot R (next 2 ks-steps) for the NEXT phase. 1:1 weave.
  // CA[0..3]=A q-lo, CA[4..7]=A q-hi; CB[0..1]=B q-lo, CB[2..3]=B q-hi.
#define QMRD2(CA, CB, RA, RB, d, qlo, qhi) do { \
    RA[0] = FRA32(d, 0, qlo);  acc[0][0] = MF(CA[0], CB[0], acc[0][0]); \
    RA[1] = FRA32(d, 1, qlo);  acc[0][1] = MF(CA[0], CB[1], acc[0][1]); \
    RA[2] = FRA32(d, 2, qlo);  acc[1][0] = MF(CA[1], CB[0], acc[1][0]); \
    RA[3] = FRA32(d, 3, qlo);  acc[1][1] = MF(CA[1], CB[1], acc[1][1]); \
    RA[4] = FRA32(d, 0, qhi);  acc[2][0] = MF(CA[2], CB[0], acc[2][0]); \
    RA[5] = FRA32(d, 1, qhi);  acc[2][1] = MF(CA[2], CB[1], acc[2][1]); \
    RA[6] = FRA32(d, 2, qhi);  acc[3][0] = MF(CA[3], CB[0], acc[3][0]); \
    RA[7] = FRA32(d, 3, qhi);  acc[3][1] = MF(CA[3], CB[1], acc[3][1]); \
    RB[0] = FRB32(d, 0, qlo);  acc[0][0] = MF(CA[4], CB[2], acc[0][0]); \
    RB[1] = FRB32(d, 1, qlo);  acc[0][1] = MF(CA[4], CB[3], acc[0][1]); \
    RB[2] = FRB32(d, 0, qhi);  acc[1][0] = MF(CA[5], CB[2], acc[1][0]); \
    RB[3] = FRB32(d, 1, qhi);  acc[1][1] = MF(CA[5], CB[3], acc[1][1]); \
    acc[2][0] = MF(CA[6], CB[2], acc[2][0]); \
    acc[2][1] = MF(CA[6], CB[3], acc[2][1]); \
    acc[3][0] = MF(CA[7], CB[2], acc[3][0]); \
    acc[3][1] = MF(CA[7], CB[3], acc[3][1]); \
  } while (0)

  // ---- prologue: tile0 -> buf0, tile1 -> buf1; prime P = buf0 q0,q1 ----
  STG(0,      Abase);                 // t0 A lo
  STG(16384,  Abase + 16384);         // t0 A hi
  STG(32768,  Bbase);                 // t0 B lo
  STG(49152,  Bbase + 16384);         // t0 B hi
  STG(65536,  Abase + ktA);           // t1 A lo
  STG(81920,  Abase + ktA + 16384);   // t1 A hi
  STG(98304,  Bbase + ktB);           // t1 B lo
  STG(114688, Bbase + ktB + 16384);   // t1 B hi
  VMN8();   // tile0's 8 landed (tile1's 8 in flight)
  BARX();

  bf16x8 Pa[8], Pb[4], Qa[8], Qb[4];
#pragma unroll
  for (int i = 0; i < 4; ++i) { Pa[i] = FRA32(0, i, 0); Pa[4 + i] = FRA32(0, i, 1); }
#pragma unroll
  for (int j = 0; j < 2; ++j) { Pb[j] = FRB32(0, j, 0); Pb[2 + j] = FRB32(0, j, 1); }

  const int T2 = K >> 7;  // iterations of 2 K64-tiles (4 merged phases each)
  for (int t = 0; t < T2; ++t) {
    const int u2 = 2 * t + 2, u3 = 2 * t + 3;
    const char* A2 = Abase + (size_t)(u2 < NT ? u2 : NT - 1) * ktA;
    const char* B2 = Bbase + (size_t)(u2 < NT ? u2 : NT - 1) * ktB;
    const char* A3 = Abase + (size_t)(u3 < NT ? u3 : NT - 1) * ktA;
    const char* B3 = Bbase + (size_t)(u3 < NT ? u3 : NT - 1) * ktB;

    // mph0: MFMA tile2t q0q1 (P); read buf0 q2q3 -> Q;
    //       VM0 (tile 2t+1 landed, staged mph3-prev/prologue) -> BARX
    QMRD2(Pa, Pb, Qa, Qb, 0, 2, 3);
    PIN12();
    VM0();
    BARX();

    // mph1: MFMA tile2t q2q3 (Q); read buf1 tile(2t+1) q0q1 -> P;
    //       stage tile(2t+2) A+B -> buf0 (buf0 last read mph0, 1 barrier)
    STG(0,     A2);
    STG(16384, A2 + 16384);
    STG(32768, B2);
    STG(49152, B2 + 16384);
    QMRD2(Qa, Qb, Pa, Pb, 1, 0, 1);
    PINV8(); PIN12();
    BARX();

    // mph2: MFMA tile(2t+1) q0q1 (P); read buf1 q2q3 -> Q;
    //       VM0 (tile 2t+2 landed, staged mph1) -> BARX
    QMRD2(Pa, Pb, Qa, Qb, 1, 2, 3);
    PIN12();
    VM0();
    BARX();

    // mph3: MFMA tile(2t+1) q2q3 (Q); read buf0 tile(2t+2) q0q1 -> P;
    //       stage tile(2t+3) A+B -> buf1 (buf1 last read mph2, 1 barrier)
    STG(65536,  A3);
    STG(81920,  A3 + 16384);
    STG(98304,  B3);
    STG(114688, B3 + 16384);
    QMRD2(Qa, Qb, Pa, Pb, 0, 0, 1);
    PINV8(); PIN12();
    BARX();
  }
  VM0();  // drain in-flight DMA before teardown

  // ---- epilogue: +bias, f32 store ----
  // C/D 32x32: col = lane&31, row = (reg&3) + 8*(reg>>2) + 4*(lane>>5)
#pragma unroll
  for (int i = 0; i < 4; ++i) {
#pragma unroll
    for (int j2 = 0; j2 < 2; ++j2) {
      const size_t col = n0 + wc * 64 + j2 * 32 + l31;
      const float bv = bias[col];
      const size_t rbase = m0 + wr * 128 + i * 32 + lhi * 4;
#pragma unroll
      for (int r = 0; r < 16; ++r) {
        const size_t row = rbase + (r & 3) + 8 * (r >> 2);
        C[row * N + col] = acc[i][j2][r] + bv;
      }
    }
  }
}

// ---------- naive f32 fallback (shape mismatch only) ----------
__global__ void gemm_naive(const float* __restrict__ x, const float* __restrict__ w,
                           const float* __restrict__ b, float* __restrict__ out,
                           int M, int N, int K) {
  int n = blockIdx.x * blockDim.x + threadIdx.x;
  int m = blockIdx.y;
  if (n >= N || m >= M) return;
  float acc = 0.f;
  for (int k = 0; k < K; ++k) {
    float wv = w[(size_t)n * K + k];
    float s = (wv > 0.f) ? 1.f : ((wv < 0.f) ? -1.f : 0.f);
    acc += x[(size_t)m * K + k] * s;
  }
  out[(size_t)m * N + n] = acc + b[n];
}

extern "C" void kernel_launch(void* const* d_in, const int* in_sizes, int n_in,
                              void* d_out, int out_size, void* d_ws, size_t ws_size,
                              hipStream_t stream) {
  const float* x = (const float*)d_in[0];
  const float* w = (const float*)d_in[1];
  const float* b = (const float*)d_in[2];
  float* out = (float*)d_out;

  const int N = in_sizes[2];
  const int K = in_sizes[1] / N;
  const int M = in_sizes[0] / K;

  const size_t need = ((size_t)M * K + (size_t)N * K) * sizeof(uint16_t);
  const bool big_ok = (M % 256 == 0) && (N % 256 == 0) && (K % 256 == 0) &&
                      (((M / 256) * (N / 256)) % 8 == 0) && (ws_size >= need);
  if (!big_ok) {
    hipLaunchKernelGGL(gemm_naive, dim3((N + 255) / 256, M), dim3(256), 0, stream,
                       x, w, b, out, M, N, K);
    return;
  }

  uint16_t* Xf = (uint16_t*)d_ws;
  uint16_t* Wf = Xf + (size_t)M * K;

  hipLaunchKernelGGL(prep_frag, dim3(2048), dim3(256), 0, stream,
                     x, (uint4*)Xf, M, w, (uint4*)Wf, N, K);

  hipLaunchKernelGGL(gemm256, dim3((M / 256) * (N / 256)), dim3(512), 0, stream,
                     Xf, Wf, b, out, M, N, K);
}